// Round 1
// baseline (2308.105 us; speedup 1.0000x reference)
//
#include <hip/hip_runtime.h>
#include <hip/hip_bf16.h>

#define NEDGE 640000
#define NMAX  40000

// ---------------------------------------------------------------- helpers
__device__ inline void atomicMaxF(float* addr, float val) {
    unsigned* ua = (unsigned*)addr;
    unsigned old = *ua;
    while (__uint_as_float(old) < val) {
        unsigned assumed = old;
        old = atomicCAS(ua, assumed, __float_as_uint(val));
        if (old == assumed) break;
    }
}

__device__ inline unsigned orderKey(float s) {
    unsigned b = __float_as_uint(s);
    return (b & 0x80000000u) ? ~b : (b | 0x80000000u);
}

__device__ const float c_invk[10] = {
    1.0f/32000.0f, 1.0f/25600.0f, 1.0f/20480.0f, 1.0f/16384.0f, 1.0f/13108.0f,
    1.0f/10487.0f, 1.0f/8390.0f,  1.0f/6712.0f,  1.0f/5370.0f,  1.0f/4296.0f };

// ---------------------------------------------------------------- init
// blocks 0..9: init rbuf (max part = -inf, sum part = 0) and pnorm[b]
// all blocks: copy edge_index -> esrc/edst
__global__ void k_init(const int* __restrict__ eidx, int* __restrict__ esrc,
                       int* __restrict__ edst, const float* __restrict__ poolp,
                       float* __restrict__ rbuf, float* __restrict__ pnorm) {
    int b = blockIdx.x, t = threadIdx.x;
    if (b < 10) {
        rbuf[b*256 + t] = (t < 128) ? -3.402823e38f : 0.0f;
        __shared__ float red[256];
        float v = 0.0f;
        if (t < 128) { float pv = poolp[b*128 + t]; v = pv*pv; }
        red[t] = v; __syncthreads();
        for (int s = 128; s > 0; s >>= 1) { if (t < s) red[t] += red[t+s]; __syncthreads(); }
        if (t == 0) pnorm[b] = sqrtf(red[0]);
    }
    int e = b*256 + t;
    if (e < NEDGE) { esrc[e] = eidx[e]; edst[e] = eidx[NEDGE + e]; }
}

// ---------------------------------------------------------------- degree
__global__ void k_deg(const int* __restrict__ esrc, const int* __restrict__ edst,
                      int* __restrict__ deg) {
    int e = blockIdx.x*256 + threadIdx.x;
    if (e >= NEDGE) return;
    int s = esrc[e];
    if (s < 0) return;
    atomicAdd(&deg[edst[e]], 1);
}

// ---------------------------------------------------------------- scan (offs/cursor/dinv)
__global__ __launch_bounds__(1024) void k_scan(const int* __restrict__ deg,
                                               int* __restrict__ offs, int* __restrict__ cursor,
                                               float* __restrict__ dinv, int n) {
    __shared__ int wsum[16], wexcl[16];
    __shared__ int s_carry, s_total;
    int t = threadIdx.x, lane = t & 63, wid = t >> 6;
    if (t == 0) s_carry = 0;
    __syncthreads();
    for (int base = 0; base < n; base += 4096) {
        int i0 = base + t*4;
        int a0 = (i0   < n) ? deg[i0]   : 0;
        int a1 = (i0+1 < n) ? deg[i0+1] : 0;
        int a2 = (i0+2 < n) ? deg[i0+2] : 0;
        int a3 = (i0+3 < n) ? deg[i0+3] : 0;
        int tsum = a0+a1+a2+a3;
        int incl = tsum;
        for (int off = 1; off < 64; off <<= 1) {
            int o = __shfl_up(incl, off);
            if (lane >= off) incl += o;
        }
        if (lane == 63) wsum[wid] = incl;
        __syncthreads();
        if (t == 0) { int c = 0; for (int w = 0; w < 16; w++) { wexcl[w] = c; c += wsum[w]; } s_total = c; }
        __syncthreads();
        int carry = s_carry;
        int p0 = carry + wexcl[wid] + (incl - tsum);
        int p1 = p0+a0, p2 = p1+a1, p3 = p2+a2;
        if (i0   < n) { offs[i0]  = p0; cursor[i0]  = p0; dinv[i0]  = (a0>0)?1.0f/sqrtf((float)a0):0.0f; }
        if (i0+1 < n) { offs[i0+1]= p1; cursor[i0+1]= p1; dinv[i0+1]= (a1>0)?1.0f/sqrtf((float)a1):0.0f; }
        if (i0+2 < n) { offs[i0+2]= p2; cursor[i0+2]= p2; dinv[i0+2]= (a2>0)?1.0f/sqrtf((float)a2):0.0f; }
        if (i0+3 < n) { offs[i0+3]= p3; cursor[i0+3]= p3; dinv[i0+3]= (a3>0)?1.0f/sqrtf((float)a3):0.0f; }
        __syncthreads();
        if (t == 0) s_carry = carry + s_total;
        __syncthreads();
    }
}

// ---------------------------------------------------------------- CSR fill
__global__ void k_fill(const int* __restrict__ esrc, const int* __restrict__ edst,
                       int* __restrict__ cursor, int* __restrict__ csr) {
    int e = blockIdx.x*256 + threadIdx.x;
    if (e >= NEDGE) return;
    int s = esrc[e];
    if (s < 0) return;
    int pos = atomicAdd(&cursor[edst[e]], 1);
    csr[pos] = s;
}

// ---------------------------------------------------------------- GEMM: HW = h@W, AGG = h@V + bias
#define GRB 32
__global__ __launch_bounds__(128) void k_gemm(const float* __restrict__ h,
                                              const float* __restrict__ W, const float* __restrict__ V,
                                              const float* __restrict__ bias,
                                              float* __restrict__ HW, float* __restrict__ AGG, int n) {
    __shared__ __align__(16) float ht[128*36];   // [k][r], stride 36 keeps float4 alignment
    int t = threadIdx.x;
    int v0 = blockIdx.x * GRB;
    for (int it = 0; it < GRB; it++) {
        ht[t*36 + it] = h[(v0 + it)*128 + t];     // rows past n read finite garbage; stores guarded
    }
    __syncthreads();
    float accW[GRB], accV[GRB];
    #pragma unroll
    for (int r = 0; r < GRB; r++) { accW[r] = 0.0f; accV[r] = 0.0f; }
    for (int k = 0; k < 128; k++) {
        float mw = W[k*128 + t];
        float mv = V[k*128 + t];
        const float* hp = &ht[k*36];
        #pragma unroll
        for (int r4 = 0; r4 < GRB; r4 += 4) {
            float4 hq = *(const float4*)(hp + r4);
            accW[r4+0] += hq.x*mw;  accV[r4+0] += hq.x*mv;
            accW[r4+1] += hq.y*mw;  accV[r4+1] += hq.y*mv;
            accW[r4+2] += hq.z*mw;  accV[r4+2] += hq.z*mv;
            accW[r4+3] += hq.w*mw;  accV[r4+3] += hq.w*mv;
        }
    }
    float b = bias[t];
    for (int r = 0; r < GRB; r++) {
        int v = v0 + r;
        if (v >= n) break;
        HW[v*128 + t]  = accW[r];
        AGG[v*128 + t] = accV[r] + b;
    }
}

// ---------------------------------------------------------------- layer-0 fused node update
__global__ __launch_bounds__(128) void k_gather0(
    const float* __restrict__ x, const float* __restrict__ W1, const float* __restrict__ V1,
    const float* __restrict__ convb,
    const float* __restrict__ bng, const float* __restrict__ bnb,
    const float* __restrict__ bnm, const float* __restrict__ bnv,
    const float* __restrict__ poolp, const float* __restrict__ pnorm,
    const float* __restrict__ prelua,
    const int* __restrict__ offs, const int* __restrict__ deg, const float* __restrict__ dinv,
    const int* __restrict__ csr,
    float* __restrict__ AGG, float* __restrict__ score, unsigned* __restrict__ keys) {
    int v = blockIdx.x, j = threadIdx.x;
    __shared__ float red[128];
    int off = offs[v], dg = deg[v];
    float accs = 0.0f;
    for (int c = j; c < dg; c += 128) { int s = csr[off + c]; accs += x[s]*dinv[s]; }
    red[j] = accs; __syncthreads();
    for (int st = 64; st > 0; st >>= 1) { if (j < st) red[j] += red[j+st]; __syncthreads(); }
    float aggs = red[0] * dinv[v];
    __syncthreads();
    float h2 = aggs*W1[j] + x[v]*V1[j] + convb[j];
    h2 = fmaxf(h2, 0.0f);
    float scale = bng[j] / sqrtf(bnv[j] + 1e-5f);
    h2 = (h2 - bnm[j])*scale + bnb[j];
    float a = prelua[0];
    h2 = (h2 > 0.0f) ? h2 : a*h2;
    AGG[v*128 + j] = h2;
    red[j] = h2 * poolp[j]; __syncthreads();
    for (int st = 64; st > 0; st >>= 1) { if (j < st) red[j] += red[j+st]; __syncthreads(); }
    if (j == 0) {
        float sc = tanhf(red[0] / pnorm[0]);
        score[v] = sc;
        keys[v]  = orderKey(sc);
    }
}

// ---------------------------------------------------------------- generic fused gather + node update + score
__global__ __launch_bounds__(128) void k_gather(
    const float* __restrict__ HW, float* __restrict__ AGG,
    const int* __restrict__ offs, const int* __restrict__ deg, const float* __restrict__ dinv,
    const int* __restrict__ csr,
    const float* __restrict__ bng, const float* __restrict__ bnb,
    const float* __restrict__ bnm, const float* __restrict__ bnv,
    const float* __restrict__ poolp, const float* __restrict__ pnorm,
    const float* __restrict__ prelua,
    float* __restrict__ score, unsigned* __restrict__ keys, int layer) {
    int v = blockIdx.x, j = threadIdx.x;
    __shared__ int   s_src[128];
    __shared__ float s_dv[128];
    __shared__ float red[128];
    int off = offs[v], dg = deg[v];
    float acc = 0.0f;
    for (int base = 0; base < dg; base += 128) {
        int cnt = min(128, dg - base);
        if (j < cnt) { int s = csr[off + base + j]; s_src[j] = s; s_dv[j] = dinv[s]; }
        __syncthreads();
        for (int c = 0; c < cnt; c++) acc += HW[s_src[c]*128 + j] * s_dv[c];
        __syncthreads();
    }
    int gj = layer*128 + j;
    float h2 = AGG[v*128 + j] + acc*dinv[v];     // AGG holds h@V + bias
    h2 = fmaxf(h2, 0.0f);
    float scale = bng[gj] / sqrtf(bnv[gj] + 1e-5f);
    h2 = (h2 - bnm[gj])*scale + bnb[gj];
    float a = prelua[0];
    h2 = (h2 > 0.0f) ? h2 : a*h2;
    AGG[v*128 + j] = h2;
    red[j] = h2 * poolp[gj]; __syncthreads();
    for (int st = 64; st > 0; st >>= 1) { if (j < st) red[j] += red[j+st]; __syncthreads(); }
    if (j == 0) {
        float sc = tanhf(red[0] / pnorm[layer]);
        score[v] = sc;
        keys[v]  = orderKey(sc);
    }
}

// ---------------------------------------------------------------- top-k: radix select + stable-by-index compaction
__global__ __launch_bounds__(1024) void k_topk(const unsigned* __restrict__ keys,
                                               int* __restrict__ remap, int* __restrict__ keep_ids,
                                               int n, int k) {
    __shared__ int hist[256];
    __shared__ unsigned sh_prefix;
    __shared__ int sh_rem;
    int t = threadIdx.x, lane = t & 63, wid = t >> 6;
    if (t == 0) { sh_prefix = 0u; sh_rem = k; }
    for (int pass = 0; pass < 4; pass++) {
        int shift = 24 - 8*pass;
        __syncthreads();
        if (t < 256) hist[t] = 0;
        __syncthreads();
        unsigned pfx = sh_prefix;
        for (int i = t; i < n; i += 1024) {
            unsigned key = keys[i];
            bool match = (pass == 0) || ((key >> (shift+8)) == (pfx >> (shift+8)));
            int d = (key >> shift) & 255;
            unsigned long long act = __ballot(match);
            if (match) {
                unsigned long long m = act;
                for (int b = 0; b < 8; b++) {
                    unsigned long long bal = __ballot((d >> b) & 1);
                    m &= ((d >> b) & 1) ? bal : ~bal;
                }
                m &= act;
                int leader = __ffsll((unsigned long long)m) - 1;
                if (lane == leader) atomicAdd(&hist[d], __popcll(m));
            }
        }
        __syncthreads();
        if (t == 0) {
            int rem = sh_rem, cum = 0, d = 255;
            for (; d > 0; d--) { if (cum + hist[d] >= rem) break; cum += hist[d]; }
            sh_rem = rem - cum;
            sh_prefix = pfx | ((unsigned)d << shift);
        }
    }
    __syncthreads();
    unsigned thresh = sh_prefix;
    int ntk = sh_rem;                 // ties (==thresh) to keep, lowest index first
    // phase B: pair scan over (count_gt, count_tie), slots assigned in index order
    __shared__ unsigned long long bsum[16], bexcl[16];
    __shared__ unsigned long long b_carry, b_total;
    if (t == 0) b_carry = 0ULL;
    __syncthreads();
    for (int base = 0; base < n; base += 4096) {
        int i0 = base + t*4;
        unsigned long long e[4];
        unsigned kx[4];
        #pragma unroll
        for (int q = 0; q < 4; q++) {
            int i = i0 + q;
            unsigned key = (i < n) ? keys[i] : 0u;
            kx[q] = key;
            unsigned long long g  = (i < n && key >  thresh) ? 1ULL : 0ULL;
            unsigned long long ti = (i < n && key == thresh) ? (1ULL << 32) : 0ULL;
            e[q] = g | ti;
        }
        unsigned long long tsum = e[0]+e[1]+e[2]+e[3];
        unsigned long long incl = tsum;
        for (int off = 1; off < 64; off <<= 1) {
            unsigned long long o = __shfl_up(incl, (unsigned)off);
            if (lane >= off) incl += o;
        }
        if (lane == 63) bsum[wid] = incl;
        __syncthreads();
        if (t == 0) { unsigned long long c = 0; for (int w = 0; w < 16; w++) { bexcl[w] = c; c += bsum[w]; } b_total = c; }
        __syncthreads();
        unsigned long long before = b_carry + bexcl[wid] + (incl - tsum);
        #pragma unroll
        for (int q = 0; q < 4; q++) {
            int i = i0 + q;
            if (i < n) {
                int cg = (int)(before & 0xffffffffULL);
                int ct = (int)(before >> 32);
                unsigned key = kx[q];
                bool g  = key >  thresh;
                bool ti = key == thresh;
                bool keep = g || (ti && ct < ntk);
                int slot = cg + min(ct, ntk);
                remap[i] = keep ? slot : -1;
                if (keep) keep_ids[slot] = i;
            }
            before += e[q];
        }
        __syncthreads();
        if (t == 0) b_carry = b_carry + b_total;
        __syncthreads();
    }
}

// ---------------------------------------------------------------- pool (h' = h[idx]*score, max/mean reads) + edge remap
#define PB 128
__global__ void k_pool(const float* __restrict__ AGG, const float* __restrict__ score,
                       const int* __restrict__ keep_ids, const int* __restrict__ remap,
                       float* __restrict__ H, float* __restrict__ rbuf,
                       int* __restrict__ esrc, int* __restrict__ edst, int k, int layer) {
    int b = blockIdx.x;
    if (b < PB) {
        int sub = threadIdx.x >> 7, j = threadIdx.x & 127;
        float lmax = -3.402823e38f, lsum = 0.0f;
        for (int s = b*2 + sub; s < k; s += PB*2) {
            int v = keep_ids[s];
            float val = AGG[v*128 + j] * score[v];
            H[s*128 + j] = val;
            lmax = fmaxf(lmax, val);
            lsum += val;
        }
        __shared__ float shm[256], shs[256];
        shm[threadIdx.x] = lmax; shs[threadIdx.x] = lsum;
        __syncthreads();
        if (sub == 0) {
            lmax = fmaxf(shm[j], shm[j+128]);
            lsum = shs[j] + shs[j+128];
            atomicMaxF(&rbuf[layer*256 + j], lmax);
            atomicAdd(&rbuf[layer*256 + 128 + j], lsum);
        }
    } else {
        int e = (b - PB)*256 + threadIdx.x;
        if (e < NEDGE) {
            int s = esrc[e];
            if (s >= 0) {
                int ns = remap[s], nd = remap[edst[e]];
                if (ns < 0 || nd < 0) esrc[e] = -1;
                else { esrc[e] = ns; edst[e] = nd; }
            }
        }
    }
}

// ---------------------------------------------------------------- MLP head
__global__ void k_lin1(const float* __restrict__ rbuf, const float* __restrict__ w1,
                       float* __restrict__ z1pre) {
    int kc = blockIdx.x / 5, jc = blockIdx.x % 5;
    int j = jc*256 + threadIdx.x;
    float acc = 0.0f;
    for (int i = kc*256; i < kc*256 + 256; i++) {
        float rv = rbuf[i];
        if ((i & 255) >= 128) rv *= c_invk[i >> 8];   // mean = sum / k
        acc += rv * w1[i*1280 + j];
    }
    atomicAdd(&z1pre[j], acc);
}

__global__ __launch_bounds__(256) void k_lin2(const float* __restrict__ z1pre, const float* __restrict__ b1,
                                              const float* __restrict__ w2, const float* __restrict__ b2,
                                              const float* __restrict__ prelua, float* __restrict__ out) {
    int t = threadIdx.x;
    float a = prelua[0];
    float acc[8];
    #pragma unroll
    for (int o = 0; o < 8; o++) acc[o] = 0.0f;
    for (int kk = t; kk < 1280; kk += 256) {
        float z = z1pre[kk] + b1[kk];
        z = (z > 0.0f) ? z : a*z;
        #pragma unroll
        for (int o = 0; o < 8; o++) acc[o] += z * w2[kk*8 + o];
    }
    __shared__ float red[256];
    __shared__ float zo[8];
    for (int o = 0; o < 8; o++) {
        red[t] = acc[o]; __syncthreads();
        for (int s = 128; s > 0; s >>= 1) { if (t < s) red[t] += red[t+s]; __syncthreads(); }
        if (t == 0) { float z = red[0] + b2[o]; zo[o] = (z > 0.0f) ? z : a*z; }
        __syncthreads();
    }
    if (t == 0) {
        float mn = zo[0];
        for (int o = 1; o < 8; o++) mn = fminf(mn, zo[o]);
        float v[8], mx = -3.402823e38f;
        for (int o = 0; o < 8; o++) { v[o] = zo[o] - mn; mx = fmaxf(mx, v[o]); }
        float sm = 0.0f;
        for (int o = 0; o < 8; o++) { v[o] = v[o] / mx; sm += v[o]; }
        for (int o = 0; o < 8; o++) out[o] = v[o] / sm;
    }
}

// ---------------------------------------------------------------- launch
extern "C" void kernel_launch(void* const* d_in, const int* in_sizes, int n_in,
                              void* d_out, int out_size, void* d_ws, size_t ws_size,
                              hipStream_t stream) {
    const float* x      = (const float*)d_in[0];
    const int*   eidx   = (const int*)  d_in[1];
    const float* W1     = (const float*)d_in[2];
    const float* V1     = (const float*)d_in[3];
    const float* Ws     = (const float*)d_in[4];
    const float* Vs     = (const float*)d_in[5];
    const float* convb  = (const float*)d_in[6];
    const float* bng    = (const float*)d_in[7];
    const float* bnb    = (const float*)d_in[8];
    const float* bnm    = (const float*)d_in[9];
    const float* bnv    = (const float*)d_in[10];
    const float* poolp  = (const float*)d_in[11];
    const float* prelua = (const float*)d_in[12];
    const float* w1     = (const float*)d_in[13];
    const float* b1     = (const float*)d_in[14];
    const float* w2     = (const float*)d_in[15];
    const float* b2     = (const float*)d_in[16];
    float* out = (float*)d_out;

    // workspace layout (~71 MB)
    float* wsf  = (float*)d_ws;
    float* H    = wsf;                       // NMAX*128
    float* HW   = H    + (size_t)NMAX*128;
    float* AGG  = HW   + (size_t)NMAX*128;
    float* dinv = AGG  + (size_t)NMAX*128;
    float* score= dinv + NMAX;
    float* rbuf = score+ NMAX;               // 2560
    float* pnorm= rbuf + 2560;               // 16
    float* z1pre= pnorm+ 16;                 // 1280
    unsigned* keys = (unsigned*)(z1pre + 1280);  // NMAX
    int* esrc   = (int*)(keys + NMAX);
    int* edst   = esrc + NEDGE;
    int* csr    = edst + NEDGE;
    int* deg    = csr  + NEDGE;
    int* offs   = deg  + NMAX;
    int* cursor = offs + NMAX;
    int* remap  = cursor + NMAX;
    int* keep_ids = remap + NMAX;

    static const int NS[10] = {40000,32000,25600,20480,16384,13108,10487,8390,6712,5370};
    static const int KS[10] = {32000,25600,20480,16384,13108,10487,8390,6712,5370,4296};

    k_init<<<2500, 256, 0, stream>>>(eidx, esrc, edst, poolp, rbuf, pnorm);
    hipMemsetAsync(z1pre, 0, 1280*sizeof(float), stream);

    for (int i = 0; i < 10; i++) {
        int n = NS[i], k = KS[i];
        hipMemsetAsync(deg, 0, (size_t)n*sizeof(int), stream);
        k_deg <<<2500, 256, 0, stream>>>(esrc, edst, deg);
        k_scan<<<1, 1024, 0, stream>>>(deg, offs, cursor, dinv, n);
        k_fill<<<2500, 256, 0, stream>>>(esrc, edst, cursor, csr);
        if (i == 0) {
            k_gather0<<<n, 128, 0, stream>>>(x, W1, V1, convb,
                                             bng, bnb, bnm, bnv, poolp, pnorm, prelua,
                                             offs, deg, dinv, csr, AGG, score, keys);
        } else {
            k_gemm<<<(n + GRB - 1)/GRB, 128, 0, stream>>>(H, Ws + (size_t)(i-1)*16384,
                                                          Vs + (size_t)(i-1)*16384,
                                                          convb + i*128, HW, AGG, n);
            k_gather<<<n, 128, 0, stream>>>(HW, AGG, offs, deg, dinv, csr,
                                            bng, bnb, bnm, bnv, poolp, pnorm, prelua,
                                            score, keys, i);
        }
        k_topk<<<1, 1024, 0, stream>>>(keys, remap, keep_ids, n, k);
        k_pool<<<PB + 2500, 256, 0, stream>>>(AGG, score, keep_ids, remap, H, rbuf,
                                              esrc, edst, k, i);
    }

    k_lin1<<<50, 256, 0, stream>>>(rbuf, w1, z1pre);
    k_lin2<<<1, 256, 0, stream>>>(z1pre, b1, w2, b2, prelua, out);
}

// Round 2
// 2236.460 us; speedup vs baseline: 1.0320x; 1.0320x over previous
//
#include <hip/hip_runtime.h>
#include <hip/hip_bf16.h>

#define NEDGE 640000
#define NMAX  40000
#define SB    40      // scan blocks

// ---------------------------------------------------------------- helpers
__device__ inline void atomicMaxF(float* addr, float val) {
    unsigned* ua = (unsigned*)addr;
    unsigned old = *ua;
    while (__uint_as_float(old) < val) {
        unsigned assumed = old;
        old = atomicCAS(ua, assumed, __float_as_uint(val));
        if (old == assumed) break;
    }
}

__device__ inline unsigned orderKey(float s) {
    unsigned b = __float_as_uint(s);
    return (b & 0x80000000u) ? ~b : (b | 0x80000000u);
}

__device__ const float c_invk[10] = {
    1.0f/32000.0f, 1.0f/25600.0f, 1.0f/20480.0f, 1.0f/16384.0f, 1.0f/13108.0f,
    1.0f/10487.0f, 1.0f/8390.0f,  1.0f/6712.0f,  1.0f/5370.0f,  1.0f/4296.0f };

// selbuf slots: 0=bstar 1=rem 2=candcnt 3=thresh 4=cut 5=slotcnt

// ---------------------------------------------------------------- init
__global__ void k_init(const int* __restrict__ eidx, int* __restrict__ esrc,
                       int* __restrict__ edst, const float* __restrict__ poolp,
                       float* __restrict__ rbuf, float* __restrict__ pnorm,
                       int* __restrict__ ecnt) {
    int b = blockIdx.x, t = threadIdx.x;
    if (b < 10) {
        rbuf[b*256 + t] = (t < 128) ? -3.402823e38f : 0.0f;
        __shared__ float red[256];
        float v = 0.0f;
        if (t < 128) { float pv = poolp[b*128 + t]; v = pv*pv; }
        red[t] = v; __syncthreads();
        for (int s = 128; s > 0; s >>= 1) { if (t < s) red[t] += red[t+s]; __syncthreads(); }
        if (t == 0) pnorm[b] = sqrtf(red[0]);
    }
    if (b == 10 && t < 16) ecnt[t] = (t == 0) ? NEDGE : 0;
    int e = b*256 + t;
    if (e < NEDGE) { esrc[e] = eidx[e]; edst[e] = eidx[NEDGE + e]; }
}

// ---------------------------------------------------------------- degree (compacted edges)
__global__ void k_deg(const int* __restrict__ esrc, const int* __restrict__ edst,
                      int* __restrict__ deg, const int* __restrict__ ecnt) {
    int e = blockIdx.x*256 + threadIdx.x;
    if (e >= *ecnt) return;
    atomicAdd(&deg[edst[e]], 1);
}

// ---------------------------------------------------------------- parallel scan (3 kernels)
__global__ void k_s1(const int* __restrict__ deg, int* __restrict__ bpart, int n, int chunk) {
    int b = blockIdx.x, t = threadIdx.x;
    int start = b*chunk, end = min(start + chunk, n);
    int s = 0;
    for (int i = start + t; i < end; i += 256) s += deg[i];
    __shared__ int red[256];
    red[t] = s; __syncthreads();
    for (int st = 128; st > 0; st >>= 1) { if (t < st) red[t] += red[t+st]; __syncthreads(); }
    if (t == 0) bpart[b] = red[0];
}

__global__ void k_s2(const int* __restrict__ bpart, int* __restrict__ bexcl) {
    int t = threadIdx.x;                    // 64 threads = 1 wave
    int v = (t < SB) ? bpart[t] : 0;
    int incl = v;
    for (int off = 1; off < 64; off <<= 1) {
        int o = __shfl_up(incl, off);
        if (t >= off) incl += o;
    }
    if (t < SB) bexcl[t] = incl - v;
}

__global__ void k_s3(const int* __restrict__ deg, const int* __restrict__ bexcl,
                     int* __restrict__ offs, int* __restrict__ cursor,
                     float* __restrict__ dinv, int n, int chunk) {
    int b = blockIdx.x, t = threadIdx.x, lane = t & 63, wid = t >> 6;
    __shared__ int wsum[4];
    __shared__ int s_carry;
    int start = b*chunk, end = min(start + chunk, n);
    if (t == 0) s_carry = bexcl[b];
    __syncthreads();
    for (int base = start; base < end; base += 256) {
        int i = base + t;
        int d = (i < end) ? deg[i] : 0;
        int incl = d;
        for (int off = 1; off < 64; off <<= 1) {
            int o = __shfl_up(incl, off);
            if (lane >= off) incl += o;
        }
        if (lane == 63) wsum[wid] = incl;
        __syncthreads();
        if (t == 0) { int c = s_carry; for (int w = 0; w < 4; w++) { int tmp = wsum[w]; wsum[w] = c; c += tmp; } s_carry = c; }
        __syncthreads();
        int p = wsum[wid] + incl - d;
        if (i < end) {
            offs[i] = p; cursor[i] = p;
            dinv[i] = (d > 0) ? 1.0f/sqrtf((float)d) : 0.0f;
        }
        __syncthreads();
    }
}

// ---------------------------------------------------------------- CSR fill
__global__ void k_fill(const int* __restrict__ esrc, const int* __restrict__ edst,
                       int* __restrict__ cursor, int* __restrict__ csr,
                       const int* __restrict__ ecnt) {
    int e = blockIdx.x*256 + threadIdx.x;
    if (e >= *ecnt) return;
    int pos = atomicAdd(&cursor[edst[e]], 1);
    csr[pos] = esrc[e];
}

// ---------------------------------------------------------------- GEMM: HW = h@W, AGG = h@V + bias
#define GRB 32
__global__ __launch_bounds__(128) void k_gemm(const float* __restrict__ h,
                                              const float* __restrict__ W, const float* __restrict__ V,
                                              const float* __restrict__ bias,
                                              float* __restrict__ HW, float* __restrict__ AGG, int n) {
    __shared__ __align__(16) float ht[128*36];
    int t = threadIdx.x;
    int v0 = blockIdx.x * GRB;
    for (int it = 0; it < GRB; it++) {
        ht[t*36 + it] = h[(v0 + it)*128 + t];
    }
    __syncthreads();
    float accW[GRB], accV[GRB];
    #pragma unroll
    for (int r = 0; r < GRB; r++) { accW[r] = 0.0f; accV[r] = 0.0f; }
    for (int k = 0; k < 128; k++) {
        float mw = W[k*128 + t];
        float mv = V[k*128 + t];
        const float* hp = &ht[k*36];
        #pragma unroll
        for (int r4 = 0; r4 < GRB; r4 += 4) {
            float4 hq = *(const float4*)(hp + r4);
            accW[r4+0] += hq.x*mw;  accV[r4+0] += hq.x*mv;
            accW[r4+1] += hq.y*mw;  accV[r4+1] += hq.y*mv;
            accW[r4+2] += hq.z*mw;  accV[r4+2] += hq.z*mv;
            accW[r4+3] += hq.w*mw;  accV[r4+3] += hq.w*mv;
        }
    }
    float b = bias[t];
    for (int r = 0; r < GRB; r++) {
        int v = v0 + r;
        if (v >= n) break;
        HW[v*128 + t]  = accW[r];
        AGG[v*128 + t] = accV[r] + b;
    }
}

// ---------------------------------------------------------------- layer-0 fused node update
__global__ __launch_bounds__(128) void k_gather0(
    const float* __restrict__ x, const float* __restrict__ W1, const float* __restrict__ V1,
    const float* __restrict__ convb,
    const float* __restrict__ bng, const float* __restrict__ bnb,
    const float* __restrict__ bnm, const float* __restrict__ bnv,
    const float* __restrict__ poolp, const float* __restrict__ pnorm,
    const float* __restrict__ prelua,
    const int* __restrict__ offs, const int* __restrict__ deg, const float* __restrict__ dinv,
    const int* __restrict__ csr,
    float* __restrict__ AGG, float* __restrict__ score, unsigned* __restrict__ keys) {
    int v = blockIdx.x, j = threadIdx.x;
    __shared__ float red[128];
    int off = offs[v], dg = deg[v];
    float accs = 0.0f;
    for (int c = j; c < dg; c += 128) { int s = csr[off + c]; accs += x[s]*dinv[s]; }
    red[j] = accs; __syncthreads();
    for (int st = 64; st > 0; st >>= 1) { if (j < st) red[j] += red[j+st]; __syncthreads(); }
    float aggs = red[0] * dinv[v];
    __syncthreads();
    float h2 = aggs*W1[j] + x[v]*V1[j] + convb[j];
    h2 = fmaxf(h2, 0.0f);
    float scale = bng[j] / sqrtf(bnv[j] + 1e-5f);
    h2 = (h2 - bnm[j])*scale + bnb[j];
    float a = prelua[0];
    h2 = (h2 > 0.0f) ? h2 : a*h2;
    AGG[v*128 + j] = h2;
    red[j] = h2 * poolp[j]; __syncthreads();
    for (int st = 64; st > 0; st >>= 1) { if (j < st) red[j] += red[j+st]; __syncthreads(); }
    if (j == 0) {
        float sc = tanhf(red[0] / pnorm[0]);
        score[v] = sc;
        keys[v]  = orderKey(sc);
    }
}

// ---------------------------------------------------------------- generic fused gather + node update + score
__global__ __launch_bounds__(128) void k_gather(
    const float* __restrict__ HW, float* __restrict__ AGG,
    const int* __restrict__ offs, const int* __restrict__ deg, const float* __restrict__ dinv,
    const int* __restrict__ csr,
    const float* __restrict__ bng, const float* __restrict__ bnb,
    const float* __restrict__ bnm, const float* __restrict__ bnv,
    const float* __restrict__ poolp, const float* __restrict__ pnorm,
    const float* __restrict__ prelua,
    float* __restrict__ score, unsigned* __restrict__ keys, int layer) {
    int v = blockIdx.x, j = threadIdx.x;
    __shared__ int   s_src[128];
    __shared__ float s_dv[128];
    __shared__ float red[128];
    int off = offs[v], dg = deg[v];
    float acc = 0.0f;
    for (int base = 0; base < dg; base += 128) {
        int cnt = min(128, dg - base);
        if (j < cnt) { int s = csr[off + base + j]; s_src[j] = s; s_dv[j] = dinv[s]; }
        __syncthreads();
        for (int c = 0; c < cnt; c++) acc += HW[s_src[c]*128 + j] * s_dv[c];
        __syncthreads();
    }
    int gj = layer*128 + j;
    float h2 = AGG[v*128 + j] + acc*dinv[v];
    h2 = fmaxf(h2, 0.0f);
    float scale = bng[gj] / sqrtf(bnv[gj] + 1e-5f);
    h2 = (h2 - bnm[gj])*scale + bnb[gj];
    float a = prelua[0];
    h2 = (h2 > 0.0f) ? h2 : a*h2;
    AGG[v*128 + j] = h2;
    red[j] = h2 * poolp[gj]; __syncthreads();
    for (int st = 64; st > 0; st >>= 1) { if (j < st) red[j] += red[j+st]; __syncthreads(); }
    if (j == 0) {
        float sc = tanhf(red[0] / pnorm[layer]);
        score[v] = sc;
        keys[v]  = orderKey(sc);
    }
}

// ---------------------------------------------------------------- top-k, grid-parallel
// T1: 2048-bin histogram of top-11 bits
__global__ void k_hist(const unsigned* __restrict__ keys, int* __restrict__ ghist, int n) {
    __shared__ int lh[2048];
    int t = threadIdx.x;
    for (int j = t; j < 2048; j += 256) lh[j] = 0;
    __syncthreads();
    for (int i = blockIdx.x*256 + t; i < n; i += gridDim.x*256)
        atomicAdd(&lh[keys[i] >> 21], 1);
    __syncthreads();
    for (int j = t; j < 2048; j += 256) { int c = lh[j]; if (c) atomicAdd(&ghist[j], c); }
}

// T2: select threshold bin (1 block, 1024 thr)
__global__ __launch_bounds__(1024) void k_sel1(const int* __restrict__ ghist,
                                               int* __restrict__ selbuf, int kk) {
    __shared__ int sh[2048];
    int t = threadIdx.x;
    sh[t] = ghist[t]; sh[t+1024] = ghist[t+1024];
    __syncthreads();
    for (int off = 1; off < 2048; off <<= 1) {
        int v0 = sh[t]      + ((t+off < 2048)      ? sh[t+off]      : 0);
        int v1 = sh[t+1024] + ((t+1024+off < 2048) ? sh[t+1024+off] : 0);
        __syncthreads();
        sh[t] = v0; sh[t+1024] = v1;
        __syncthreads();
    }
    for (int d = t; d < 2048; d += 1024) {
        int S = sh[d], Snext = (d == 2047) ? 0 : sh[d+1];
        if (S >= kk && Snext < kk) { selbuf[0] = d; selbuf[1] = kk - Snext; }
    }
    if (t == 0) selbuf[2] = 0;
}

// T3: collect candidates in threshold bin
__global__ void k_collect(const unsigned* __restrict__ keys, int* __restrict__ selbuf,
                          unsigned* __restrict__ ckey, int* __restrict__ cidx, int n) {
    int bstar = selbuf[0];
    for (int i = blockIdx.x*256 + threadIdx.x; i < n; i += gridDim.x*256) {
        unsigned key = keys[i];
        if ((int)(key >> 21) == bstar) {
            int pos = atomicAdd(&selbuf[2], 1);
            ckey[pos] = key; cidx[pos] = i;
        }
    }
}

// T4: exact threshold + tie index cutoff (1 block, 1024 thr)
__global__ __launch_bounds__(1024) void k_refine(const unsigned* __restrict__ ckey,
                                                 const int* __restrict__ cidx,
                                                 int* __restrict__ selbuf, int n) {
    __shared__ int sh[2048];
    __shared__ int s_dA, s_remA, s_dB, s_ntk, s_lo, s_hi;
    int t = threadIdx.x;
    int m = selbuf[2], rem = selbuf[1];
    // pass A: bits 20..10
    sh[t] = 0; sh[t+1024] = 0;
    __syncthreads();
    for (int i = t; i < m; i += 1024) atomicAdd(&sh[(ckey[i] >> 10) & 2047], 1);
    __syncthreads();
    for (int off = 1; off < 2048; off <<= 1) {
        int v0 = sh[t]      + ((t+off < 2048)      ? sh[t+off]      : 0);
        int v1 = sh[t+1024] + ((t+1024+off < 2048) ? sh[t+1024+off] : 0);
        __syncthreads();
        sh[t] = v0; sh[t+1024] = v1;
        __syncthreads();
    }
    for (int d = t; d < 2048; d += 1024) {
        int S = sh[d], Sn = (d == 2047) ? 0 : sh[d+1];
        if (S >= rem && Sn < rem) { s_dA = d; s_remA = rem - Sn; }
    }
    __syncthreads();
    int dA = s_dA, remA = s_remA;
    // pass B: bits 9..0
    sh[t] = 0;
    __syncthreads();
    for (int i = t; i < m; i += 1024)
        if ((int)((ckey[i] >> 10) & 2047) == dA) atomicAdd(&sh[ckey[i] & 1023], 1);
    __syncthreads();
    for (int off = 1; off < 1024; off <<= 1) {
        int v0 = sh[t] + ((t+off < 1024) ? sh[t+off] : 0);
        __syncthreads();
        sh[t] = v0;
        __syncthreads();
    }
    for (int d = t; d < 1024; d += 1024) {
        int S = sh[d], Sn = (d == 1023) ? 0 : sh[d+1];
        if (S >= remA && Sn < remA) { s_dB = d; s_ntk = remA - Sn; }
    }
    __syncthreads();
    unsigned thresh = ((unsigned)selbuf[0] << 21) | ((unsigned)dA << 10) | (unsigned)s_dB;
    int ntk = s_ntk;
    // binary search: smallest cut with count(ties idx<=cut) >= ntk
    if (t == 0) { s_lo = 0; s_hi = n - 1; }
    __syncthreads();
    while (true) {
        int lo = s_lo, hi = s_hi;
        if (lo >= hi) break;
        int mid = (lo + hi) >> 1;
        int c = 0;
        for (int i = t; i < m; i += 1024) c += (ckey[i] == thresh && cidx[i] <= mid);
        sh[t] = c; __syncthreads();
        for (int st = 512; st > 0; st >>= 1) { if (t < st) sh[t] += sh[t+st]; __syncthreads(); }
        if (t == 0) { if (sh[0] >= ntk) s_hi = mid; else s_lo = mid + 1; }
        __syncthreads();
    }
    if (t == 0) { selbuf[3] = (int)thresh; selbuf[4] = s_lo; selbuf[5] = 0; }
}

// C: compaction with atomic slots (order irrelevant downstream)
__global__ void k_compact(const unsigned* __restrict__ keys, int* __restrict__ selbuf,
                          int* __restrict__ remap, int* __restrict__ keep_ids, int n) {
    unsigned thresh = (unsigned)selbuf[3];
    int cut = selbuf[4];
    for (int i = blockIdx.x*256 + threadIdx.x; i < n; i += gridDim.x*256) {
        unsigned key = keys[i];
        bool keep = (key > thresh) || (key == thresh && i <= cut);
        if (keep) {
            int slot = atomicAdd(&selbuf[5], 1);
            remap[i] = slot; keep_ids[slot] = i;
        } else remap[i] = -1;
    }
}

// ---------------------------------------------------------------- pool + edge remap/compact
#define PB 128
__global__ void k_pool(const float* __restrict__ AGG, const float* __restrict__ score,
                       const int* __restrict__ keep_ids, const int* __restrict__ remap,
                       float* __restrict__ H, float* __restrict__ rbuf,
                       const int* __restrict__ esrcP, const int* __restrict__ edstP,
                       int* __restrict__ esrcN, int* __restrict__ edstN,
                       const int* __restrict__ ecntP, int* __restrict__ ecntN,
                       int k, int layer) {
    int b = blockIdx.x;
    if (b < PB) {
        int sub = threadIdx.x >> 7, j = threadIdx.x & 127;
        float lmax = -3.402823e38f, lsum = 0.0f;
        for (int s = b*2 + sub; s < k; s += PB*2) {
            int v = keep_ids[s];
            float val = AGG[v*128 + j] * score[v];
            H[s*128 + j] = val;
            lmax = fmaxf(lmax, val);
            lsum += val;
        }
        __shared__ float shm[256], shs[256];
        shm[threadIdx.x] = lmax; shs[threadIdx.x] = lsum;
        __syncthreads();
        if (sub == 0) {
            lmax = fmaxf(shm[j], shm[j+128]);
            lsum = shs[j] + shs[j+128];
            atomicMaxF(&rbuf[layer*256 + j], lmax);
            atomicAdd(&rbuf[layer*256 + 128 + j], lsum);
        }
    } else {
        int e = (b - PB)*256 + threadIdx.x;
        if (e < *ecntP) {
            int ns = remap[esrcP[e]], nd = remap[edstP[e]];
            if (ns >= 0 && nd >= 0) {
                int pos = atomicAdd(ecntN, 1);
                esrcN[pos] = ns; edstN[pos] = nd;
            }
        }
    }
}

// ---------------------------------------------------------------- MLP head
__global__ void k_lin1(const float* __restrict__ rbuf, const float* __restrict__ w1,
                       float* __restrict__ z1pre) {
    int kc = blockIdx.x / 5, jc = blockIdx.x % 5;
    int j = jc*256 + threadIdx.x;
    float acc = 0.0f;
    for (int i = kc*256; i < kc*256 + 256; i++) {
        float rv = rbuf[i];
        if ((i & 255) >= 128) rv *= c_invk[i >> 8];
        acc += rv * w1[i*1280 + j];
    }
    atomicAdd(&z1pre[j], acc);
}

__global__ __launch_bounds__(256) void k_lin2(const float* __restrict__ z1pre, const float* __restrict__ b1,
                                              const float* __restrict__ w2, const float* __restrict__ b2,
                                              const float* __restrict__ prelua, float* __restrict__ out) {
    int t = threadIdx.x;
    float a = prelua[0];
    float acc[8];
    #pragma unroll
    for (int o = 0; o < 8; o++) acc[o] = 0.0f;
    for (int kk = t; kk < 1280; kk += 256) {
        float z = z1pre[kk] + b1[kk];
        z = (z > 0.0f) ? z : a*z;
        #pragma unroll
        for (int o = 0; o < 8; o++) acc[o] += z * w2[kk*8 + o];
    }
    __shared__ float red[256];
    __shared__ float zo[8];
    for (int o = 0; o < 8; o++) {
        red[t] = acc[o]; __syncthreads();
        for (int s = 128; s > 0; s >>= 1) { if (t < s) red[t] += red[t+s]; __syncthreads(); }
        if (t == 0) { float z = red[0] + b2[o]; zo[o] = (z > 0.0f) ? z : a*z; }
        __syncthreads();
    }
    if (t == 0) {
        float mn = zo[0];
        for (int o = 1; o < 8; o++) mn = fminf(mn, zo[o]);
        float v[8], mx = -3.402823e38f;
        for (int o = 0; o < 8; o++) { v[o] = zo[o] - mn; mx = fmaxf(mx, v[o]); }
        float sm = 0.0f;
        for (int o = 0; o < 8; o++) { v[o] = v[o] / mx; sm += v[o]; }
        for (int o = 0; o < 8; o++) out[o] = v[o] / sm;
    }
}

// ---------------------------------------------------------------- launch
extern "C" void kernel_launch(void* const* d_in, const int* in_sizes, int n_in,
                              void* d_out, int out_size, void* d_ws, size_t ws_size,
                              hipStream_t stream) {
    const float* x      = (const float*)d_in[0];
    const int*   eidx   = (const int*)  d_in[1];
    const float* W1     = (const float*)d_in[2];
    const float* V1     = (const float*)d_in[3];
    const float* Ws     = (const float*)d_in[4];
    const float* Vs     = (const float*)d_in[5];
    const float* convb  = (const float*)d_in[6];
    const float* bng    = (const float*)d_in[7];
    const float* bnb    = (const float*)d_in[8];
    const float* bnm    = (const float*)d_in[9];
    const float* bnv    = (const float*)d_in[10];
    const float* poolp  = (const float*)d_in[11];
    const float* prelua = (const float*)d_in[12];
    const float* w1     = (const float*)d_in[13];
    const float* b1     = (const float*)d_in[14];
    const float* w2     = (const float*)d_in[15];
    const float* b2     = (const float*)d_in[16];
    float* out = (float*)d_out;

    // workspace layout (~76 MB)
    float* wsf  = (float*)d_ws;
    float* H    = wsf;
    float* HW   = H    + (size_t)NMAX*128;
    float* AGG  = HW   + (size_t)NMAX*128;
    float* dinv = AGG  + (size_t)NMAX*128;
    float* score= dinv + NMAX;
    float* rbuf = score+ NMAX;
    float* pnorm= rbuf + 2560;
    float* z1pre= pnorm+ 16;
    unsigned* keys = (unsigned*)(z1pre + 1280);
    int* esrcA  = (int*)(keys + NMAX);
    int* edstA  = esrcA + NEDGE;
    int* esrcB  = edstA + NEDGE;
    int* edstB  = esrcB + NEDGE;
    int* csr    = edstB + NEDGE;
    int* deg    = csr  + NEDGE;      // deg[NMAX] + ghist[2048] contiguous (one memset)
    int* ghist  = deg  + NMAX;
    int* offs   = ghist + 2048;
    int* cursor = offs + NMAX;
    int* remap  = cursor + NMAX;
    int* keep_ids = remap + NMAX;
    unsigned* ckey = (unsigned*)(keep_ids + NMAX);
    int* cidx   = (int*)(ckey + NMAX);
    int* bpart  = cidx + NMAX;       // 64
    int* bexcl  = bpart + 64;        // 64
    int* ecnt   = bexcl + 64;        // 16
    int* selbuf = ecnt + 16;         // 16

    static const int NS[10] = {40000,32000,25600,20480,16384,13108,10487,8390,6712,5370};
    static const int KS[10] = {32000,25600,20480,16384,13108,10487,8390,6712,5370,4296};

    k_init<<<2500, 256, 0, stream>>>(eidx, esrcA, edstA, poolp, rbuf, pnorm, ecnt);
    hipMemsetAsync(z1pre, 0, 1280*sizeof(float), stream);

    for (int i = 0; i < 10; i++) {
        int n = NS[i], k = KS[i];
        int chunk = (n + SB - 1) / SB;
        int* esrcP = (i & 1) ? esrcB : esrcA;
        int* edstP = (i & 1) ? edstB : edstA;
        int* esrcN = (i & 1) ? esrcA : esrcB;
        int* edstN = (i & 1) ? edstA : edstB;

        hipMemsetAsync(deg, 0, (size_t)(NMAX + 2048)*sizeof(int), stream);
        k_deg <<<2500, 256, 0, stream>>>(esrcP, edstP, deg, &ecnt[i]);
        k_s1  <<<SB, 256, 0, stream>>>(deg, bpart, n, chunk);
        k_s2  <<<1, 64, 0, stream>>>(bpart, bexcl);
        k_s3  <<<SB, 256, 0, stream>>>(deg, bexcl, offs, cursor, dinv, n, chunk);
        k_fill<<<2500, 256, 0, stream>>>(esrcP, edstP, cursor, csr, &ecnt[i]);

        if (i == 0) {
            k_gather0<<<n, 128, 0, stream>>>(x, W1, V1, convb,
                                             bng, bnb, bnm, bnv, poolp, pnorm, prelua,
                                             offs, deg, dinv, csr, AGG, score, keys);
        } else {
            k_gemm<<<(n + GRB - 1)/GRB, 128, 0, stream>>>(H, Ws + (size_t)(i-1)*16384,
                                                          Vs + (size_t)(i-1)*16384,
                                                          convb + i*128, HW, AGG, n);
            k_gather<<<n, 128, 0, stream>>>(HW, AGG, offs, deg, dinv, csr,
                                            bng, bnb, bnm, bnv, poolp, pnorm, prelua,
                                            score, keys, i);
        }

        k_hist   <<<32, 256, 0, stream>>>(keys, ghist, n);
        k_sel1   <<<1, 1024, 0, stream>>>(ghist, selbuf, k);
        k_collect<<<32, 256, 0, stream>>>(keys, selbuf, ckey, cidx, n);
        k_refine <<<1, 1024, 0, stream>>>(ckey, cidx, selbuf, n);
        k_compact<<<32, 256, 0, stream>>>(keys, selbuf, remap, keep_ids, n);

        k_pool<<<PB + 2500, 256, 0, stream>>>(AGG, score, keep_ids, remap, H, rbuf,
                                              esrcP, edstP, esrcN, edstN,
                                              &ecnt[i], &ecnt[i+1], k, i);
    }

    k_lin1<<<50, 256, 0, stream>>>(rbuf, w1, z1pre);
    k_lin2<<<1, 256, 0, stream>>>(z1pre, b1, w2, b2, prelua, out);
}

// Round 3
// 1916.354 us; speedup vs baseline: 1.2044x; 1.1670x over previous
//
#include <hip/hip_runtime.h>
#include <hip/hip_bf16.h>

#define NEDGE 640000
#define NMAX  40000
#define SB    40      // scan blocks
#define PBLK  256     // pool blocks
#define EBLK  320     // edge-compact blocks

// ---------------------------------------------------------------- helpers
__device__ inline void atomicMaxF(float* addr, float val) {
    unsigned* ua = (unsigned*)addr;
    unsigned old = *ua;
    while (__uint_as_float(old) < val) {
        unsigned assumed = old;
        old = atomicCAS(ua, assumed, __float_as_uint(val));
        if (old == assumed) break;
    }
}

__device__ inline unsigned orderKey(float s) {
    unsigned b = __float_as_uint(s);
    return (b & 0x80000000u) ? ~b : (b | 0x80000000u);
}

__device__ const float c_invk[10] = {
    1.0f/32000.0f, 1.0f/25600.0f, 1.0f/20480.0f, 1.0f/16384.0f, 1.0f/13108.0f,
    1.0f/10487.0f, 1.0f/8390.0f,  1.0f/6712.0f,  1.0f/5370.0f,  1.0f/4296.0f };

// selbuf slots: 0=bstar 1=rem 2=candcnt 3=thresh 4=cut 5=slotcnt

// ---------------------------------------------------------------- init
__global__ void k_init(const int* __restrict__ eidx, int* __restrict__ esrc,
                       int* __restrict__ edst, const float* __restrict__ poolp,
                       float* __restrict__ rbuf, float* __restrict__ pnorm,
                       int* __restrict__ ecnt) {
    int b = blockIdx.x, t = threadIdx.x;
    if (b < 10) {
        rbuf[b*256 + t] = (t < 128) ? -3.402823e38f : 0.0f;
        __shared__ float red[256];
        float v = 0.0f;
        if (t < 128) { float pv = poolp[b*128 + t]; v = pv*pv; }
        red[t] = v; __syncthreads();
        for (int s = 128; s > 0; s >>= 1) { if (t < s) red[t] += red[t+s]; __syncthreads(); }
        if (t == 0) pnorm[b] = sqrtf(red[0]);
    }
    if (b == 10 && t < 16) ecnt[t] = (t == 0) ? NEDGE : 0;
    int e = b*256 + t;
    if (e < NEDGE) { esrc[e] = eidx[e]; edst[e] = eidx[NEDGE + e]; }
}

// ---------------------------------------------------------------- degree (compacted edges)
__global__ void k_deg(const int* __restrict__ esrc, const int* __restrict__ edst,
                      int* __restrict__ deg, const int* __restrict__ ecnt) {
    int e = blockIdx.x*256 + threadIdx.x;
    if (e >= *ecnt) return;
    atomicAdd(&deg[edst[e]], 1);
}

// ---------------------------------------------------------------- parallel scan (2 kernels)
__global__ void k_s1(const int* __restrict__ deg, int* __restrict__ bpart, int n, int chunk) {
    int b = blockIdx.x, t = threadIdx.x;
    int start = b*chunk, end = min(start + chunk, n);
    int s = 0;
    for (int i = start + t; i < end; i += 256) s += deg[i];
    __shared__ int red[256];
    red[t] = s; __syncthreads();
    for (int st = 128; st > 0; st >>= 1) { if (t < st) red[t] += red[t+st]; __syncthreads(); }
    if (t == 0) bpart[b] = red[0];
}

__global__ void k_s3(const int* __restrict__ deg, const int* __restrict__ bpart,
                     int* __restrict__ offs, int* __restrict__ cursor,
                     float* __restrict__ dinv, int n, int chunk) {
    int b = blockIdx.x, t = threadIdx.x, lane = t & 63, wid = t >> 6;
    __shared__ int wsum[4];
    __shared__ int s_carry;
    if (t < 64) {                       // b < SB=40 < 64: exclusive sum of bpart[0..b)
        int v = (lane < b) ? bpart[lane] : 0;
        for (int off = 32; off > 0; off >>= 1) v += __shfl_down(v, off);
        if (lane == 0) s_carry = v;
    }
    __syncthreads();
    int start = b*chunk, end = min(start + chunk, n);
    for (int base = start; base < end; base += 256) {
        int i = base + t;
        int d = (i < end) ? deg[i] : 0;
        int incl = d;
        for (int off = 1; off < 64; off <<= 1) {
            int o = __shfl_up(incl, off);
            if (lane >= off) incl += o;
        }
        if (lane == 63) wsum[wid] = incl;
        __syncthreads();
        if (t == 0) { int c = s_carry; for (int w = 0; w < 4; w++) { int tmp = wsum[w]; wsum[w] = c; c += tmp; } s_carry = c; }
        __syncthreads();
        int p = wsum[wid] + incl - d;
        if (i < end) {
            offs[i] = p; cursor[i] = p;
            dinv[i] = (d > 0) ? 1.0f/sqrtf((float)d) : 0.0f;
        }
        __syncthreads();
    }
}

// ---------------------------------------------------------------- CSR fill
__global__ void k_fill(const int* __restrict__ esrc, const int* __restrict__ edst,
                       int* __restrict__ cursor, int* __restrict__ csr,
                       const int* __restrict__ ecnt) {
    int e = blockIdx.x*256 + threadIdx.x;
    if (e >= *ecnt) return;
    int pos = atomicAdd(&cursor[edst[e]], 1);
    csr[pos] = esrc[e];
}

// ---------------------------------------------------------------- GEMM: HW = h@W, AGG = h@V + bias
#define GRB 32
__global__ __launch_bounds__(128) void k_gemm(const float* __restrict__ h,
                                              const float* __restrict__ W, const float* __restrict__ V,
                                              const float* __restrict__ bias,
                                              float* __restrict__ HW, float* __restrict__ AGG, int n) {
    __shared__ __align__(16) float ht[128*36];
    int t = threadIdx.x;
    int v0 = blockIdx.x * GRB;
    for (int it = 0; it < GRB; it++) {
        ht[t*36 + it] = h[(v0 + it)*128 + t];
    }
    __syncthreads();
    float accW[GRB], accV[GRB];
    #pragma unroll
    for (int r = 0; r < GRB; r++) { accW[r] = 0.0f; accV[r] = 0.0f; }
    for (int k = 0; k < 128; k++) {
        float mw = W[k*128 + t];
        float mv = V[k*128 + t];
        const float* hp = &ht[k*36];
        #pragma unroll
        for (int r4 = 0; r4 < GRB; r4 += 4) {
            float4 hq = *(const float4*)(hp + r4);
            accW[r4+0] += hq.x*mw;  accV[r4+0] += hq.x*mv;
            accW[r4+1] += hq.y*mw;  accV[r4+1] += hq.y*mv;
            accW[r4+2] += hq.z*mw;  accV[r4+2] += hq.z*mv;
            accW[r4+3] += hq.w*mw;  accV[r4+3] += hq.w*mv;
        }
    }
    float b = bias[t];
    for (int r = 0; r < GRB; r++) {
        int v = v0 + r;
        if (v >= n) break;
        HW[v*128 + t]  = accW[r];
        AGG[v*128 + t] = accV[r] + b;
    }
}

// ---------------------------------------------------------------- layer-0 fused node update
__global__ __launch_bounds__(128) void k_gather0(
    const float* __restrict__ x, const float* __restrict__ W1, const float* __restrict__ V1,
    const float* __restrict__ convb,
    const float* __restrict__ bng, const float* __restrict__ bnb,
    const float* __restrict__ bnm, const float* __restrict__ bnv,
    const float* __restrict__ poolp, const float* __restrict__ pnorm,
    const float* __restrict__ prelua,
    const int* __restrict__ offs, const int* __restrict__ deg, const float* __restrict__ dinv,
    const int* __restrict__ csr,
    float* __restrict__ AGG, float* __restrict__ score, unsigned* __restrict__ keys) {
    int v = blockIdx.x, j = threadIdx.x;
    __shared__ float red[128];
    int off = offs[v], dg = deg[v];
    float accs = 0.0f;
    for (int c = j; c < dg; c += 128) { int s = csr[off + c]; accs += x[s]*dinv[s]; }
    red[j] = accs; __syncthreads();
    for (int st = 64; st > 0; st >>= 1) { if (j < st) red[j] += red[j+st]; __syncthreads(); }
    float aggs = red[0] * dinv[v];
    __syncthreads();
    float h2 = aggs*W1[j] + x[v]*V1[j] + convb[j];
    h2 = fmaxf(h2, 0.0f);
    float scale = bng[j] / sqrtf(bnv[j] + 1e-5f);
    h2 = (h2 - bnm[j])*scale + bnb[j];
    float a = prelua[0];
    h2 = (h2 > 0.0f) ? h2 : a*h2;
    AGG[v*128 + j] = h2;
    red[j] = h2 * poolp[j]; __syncthreads();
    for (int st = 64; st > 0; st >>= 1) { if (j < st) red[j] += red[j+st]; __syncthreads(); }
    if (j == 0) {
        float sc = tanhf(red[0] / pnorm[0]);
        score[v] = sc;
        keys[v]  = orderKey(sc);
    }
}

// ---------------------------------------------------------------- generic fused gather + node update + score
__global__ __launch_bounds__(128) void k_gather(
    const float* __restrict__ HW, float* __restrict__ AGG,
    const int* __restrict__ offs, const int* __restrict__ deg, const float* __restrict__ dinv,
    const int* __restrict__ csr,
    const float* __restrict__ bng, const float* __restrict__ bnb,
    const float* __restrict__ bnm, const float* __restrict__ bnv,
    const float* __restrict__ poolp, const float* __restrict__ pnorm,
    const float* __restrict__ prelua,
    float* __restrict__ score, unsigned* __restrict__ keys, int layer) {
    int v = blockIdx.x, j = threadIdx.x;
    __shared__ int   s_src[128];
    __shared__ float s_dv[128];
    __shared__ float red[128];
    int off = offs[v], dg = deg[v];
    float acc = 0.0f;
    for (int base = 0; base < dg; base += 128) {
        int cnt = min(128, dg - base);
        if (j < cnt) { int s = csr[off + base + j]; s_src[j] = s; s_dv[j] = dinv[s]; }
        __syncthreads();
        for (int c = 0; c < cnt; c++) acc += HW[s_src[c]*128 + j] * s_dv[c];
        __syncthreads();
    }
    int gj = layer*128 + j;
    float h2 = AGG[v*128 + j] + acc*dinv[v];
    h2 = fmaxf(h2, 0.0f);
    float scale = bng[gj] / sqrtf(bnv[gj] + 1e-5f);
    h2 = (h2 - bnm[gj])*scale + bnb[gj];
    float a = prelua[0];
    h2 = (h2 > 0.0f) ? h2 : a*h2;
    AGG[v*128 + j] = h2;
    red[j] = h2 * poolp[gj]; __syncthreads();
    for (int st = 64; st > 0; st >>= 1) { if (j < st) red[j] += red[j+st]; __syncthreads(); }
    if (j == 0) {
        float sc = tanhf(red[0] / pnorm[layer]);
        score[v] = sc;
        keys[v]  = orderKey(sc);
    }
}

// ---------------------------------------------------------------- top-k, grid-parallel
__global__ void k_hist(const unsigned* __restrict__ keys, int* __restrict__ ghist, int n) {
    __shared__ int lh[2048];
    int t = threadIdx.x;
    for (int j = t; j < 2048; j += 256) lh[j] = 0;
    __syncthreads();
    for (int i = blockIdx.x*256 + t; i < n; i += gridDim.x*256)
        atomicAdd(&lh[keys[i] >> 21], 1);
    __syncthreads();
    for (int j = t; j < 2048; j += 256) { int c = lh[j]; if (c) atomicAdd(&ghist[j], c); }
}

__global__ __launch_bounds__(1024) void k_sel1(const int* __restrict__ ghist,
                                               int* __restrict__ selbuf, int kk) {
    __shared__ int sh[2048];
    int t = threadIdx.x;
    sh[t] = ghist[t]; sh[t+1024] = ghist[t+1024];
    __syncthreads();
    for (int off = 1; off < 2048; off <<= 1) {
        int v0 = sh[t]      + ((t+off < 2048)      ? sh[t+off]      : 0);
        int v1 = sh[t+1024] + ((t+1024+off < 2048) ? sh[t+1024+off] : 0);
        __syncthreads();
        sh[t] = v0; sh[t+1024] = v1;
        __syncthreads();
    }
    for (int d = t; d < 2048; d += 1024) {
        int S = sh[d], Snext = (d == 2047) ? 0 : sh[d+1];
        if (S >= kk && Snext < kk) { selbuf[0] = d; selbuf[1] = kk - Snext; }
    }
    if (t == 0) selbuf[2] = 0;
}

// T3: collect candidates in threshold bin (two-phase, block-aggregated atomics)
__global__ void k_collect(const unsigned* __restrict__ keys, int* __restrict__ selbuf,
                          unsigned* __restrict__ ckey, int* __restrict__ cidx, int n) {
    int bstar = selbuf[0];
    int t = threadIdx.x, lane = t & 63;
    __shared__ int s_base, s_cur;
    __shared__ int red[256];
    int cnt = 0;
    for (int base = blockIdx.x*256; base < n; base += gridDim.x*256) {
        int i = base + t;
        if (i < n && (int)(keys[i] >> 21) == bstar) cnt++;
    }
    red[t] = cnt; __syncthreads();
    for (int st = 128; st > 0; st >>= 1) { if (t < st) red[t] += red[t+st]; __syncthreads(); }
    if (t == 0) { s_base = atomicAdd(&selbuf[2], red[0]); s_cur = 0; }
    __syncthreads();
    for (int base = blockIdx.x*256; base < n; base += gridDim.x*256) {
        int i = base + t;
        bool keep = false; unsigned key = 0;
        if (i < n) { key = keys[i]; keep = ((int)(key >> 21) == bstar); }
        unsigned long long m = __ballot(keep);
        int wcnt = __popcll(m);
        int wbase = 0;
        if (lane == 0 && wcnt) wbase = atomicAdd(&s_cur, wcnt);
        wbase = __shfl(wbase, 0);
        if (keep) {
            int pos = s_base + wbase + __popcll(m & ((1ULL << lane) - 1));
            ckey[pos] = key; cidx[pos] = i;
        }
    }
}

// T4: exact threshold + tie index cutoff
__global__ __launch_bounds__(1024) void k_refine(const unsigned* __restrict__ ckey,
                                                 const int* __restrict__ cidx,
                                                 int* __restrict__ selbuf, int n) {
    __shared__ int sh[2048];
    __shared__ int s_dA, s_remA, s_dB, s_ntk, s_lo, s_hi;
    int t = threadIdx.x;
    int m = selbuf[2], rem = selbuf[1];
    sh[t] = 0; sh[t+1024] = 0;
    __syncthreads();
    for (int i = t; i < m; i += 1024) atomicAdd(&sh[(ckey[i] >> 10) & 2047], 1);
    __syncthreads();
    for (int off = 1; off < 2048; off <<= 1) {
        int v0 = sh[t]      + ((t+off < 2048)      ? sh[t+off]      : 0);
        int v1 = sh[t+1024] + ((t+1024+off < 2048) ? sh[t+1024+off] : 0);
        __syncthreads();
        sh[t] = v0; sh[t+1024] = v1;
        __syncthreads();
    }
    for (int d = t; d < 2048; d += 1024) {
        int S = sh[d], Sn = (d == 2047) ? 0 : sh[d+1];
        if (S >= rem && Sn < rem) { s_dA = d; s_remA = rem - Sn; }
    }
    __syncthreads();
    int dA = s_dA, remA = s_remA;
    sh[t] = 0;
    __syncthreads();
    for (int i = t; i < m; i += 1024)
        if ((int)((ckey[i] >> 10) & 2047) == dA) atomicAdd(&sh[ckey[i] & 1023], 1);
    __syncthreads();
    for (int off = 1; off < 1024; off <<= 1) {
        int v0 = sh[t] + ((t+off < 1024) ? sh[t+off] : 0);
        __syncthreads();
        sh[t] = v0;
        __syncthreads();
    }
    for (int d = t; d < 1024; d += 1024) {
        int S = sh[d], Sn = (d == 1023) ? 0 : sh[d+1];
        if (S >= remA && Sn < remA) { s_dB = d; s_ntk = remA - Sn; }
    }
    __syncthreads();
    unsigned thresh = ((unsigned)selbuf[0] << 21) | ((unsigned)dA << 10) | (unsigned)s_dB;
    int ntk = s_ntk;
    if (t == 0) { s_lo = 0; s_hi = n - 1; }
    __syncthreads();
    while (true) {
        int lo = s_lo, hi = s_hi;
        if (lo >= hi) break;
        int mid = (lo + hi) >> 1;
        int c = 0;
        for (int i = t; i < m; i += 1024) c += (ckey[i] == thresh && cidx[i] <= mid);
        sh[t] = c; __syncthreads();
        for (int st = 512; st > 0; st >>= 1) { if (t < st) sh[t] += sh[t+st]; __syncthreads(); }
        if (t == 0) { if (sh[0] >= ntk) s_hi = mid; else s_lo = mid + 1; }
        __syncthreads();
    }
    if (t == 0) { selbuf[3] = (int)thresh; selbuf[4] = s_lo; selbuf[5] = 0; }
}

// C: compaction (two-phase, block-aggregated atomics)
__global__ void k_compact(const unsigned* __restrict__ keys, int* __restrict__ selbuf,
                          int* __restrict__ remap, int* __restrict__ keep_ids, int n) {
    unsigned thresh = (unsigned)selbuf[3];
    int cut = selbuf[4];
    int t = threadIdx.x, lane = t & 63;
    __shared__ int s_base, s_cur;
    __shared__ int red[256];
    int cnt = 0;
    for (int base = blockIdx.x*256; base < n; base += gridDim.x*256) {
        int i = base + t;
        if (i < n) {
            unsigned key = keys[i];
            cnt += (key > thresh) || (key == thresh && i <= cut);
        }
    }
    red[t] = cnt; __syncthreads();
    for (int st = 128; st > 0; st >>= 1) { if (t < st) red[t] += red[t+st]; __syncthreads(); }
    if (t == 0) { s_base = atomicAdd(&selbuf[5], red[0]); s_cur = 0; }
    __syncthreads();
    for (int base = blockIdx.x*256; base < n; base += gridDim.x*256) {
        int i = base + t;
        bool keep = false;
        if (i < n) {
            unsigned key = keys[i];
            keep = (key > thresh) || (key == thresh && i <= cut);
        }
        unsigned long long m = __ballot(keep);
        int wcnt = __popcll(m);
        int wbase = 0;
        if (lane == 0 && wcnt) wbase = atomicAdd(&s_cur, wcnt);
        wbase = __shfl(wbase, 0);
        if (keep) {
            int slot = s_base + wbase + __popcll(m & ((1ULL << lane) - 1));
            remap[i] = slot; keep_ids[slot] = i;
        } else if (i < n) remap[i] = -1;
    }
}

// ---------------------------------------------------------------- pool + edge remap/compact
__global__ void k_pool(const float* __restrict__ AGG, const float* __restrict__ score,
                       const int* __restrict__ keep_ids, const int* __restrict__ remap,
                       float* __restrict__ H, float* __restrict__ rbuf,
                       const int* __restrict__ esrcP, const int* __restrict__ edstP,
                       int* __restrict__ esrcN, int* __restrict__ edstN,
                       const int* __restrict__ ecntP, int* __restrict__ ecntN,
                       int k, int layer) {
    int b = blockIdx.x, t = threadIdx.x;
    if (b < PBLK) {
        int sub = t >> 7, j = t & 127;
        float lmax = -3.402823e38f, lsum = 0.0f;
        int s = b*2 + sub;
        int v = (s < k) ? keep_ids[s] : 0;
        while (s < k) {
            float sc = score[v];
            float val = AGG[v*128 + j] * sc;
            int s2 = s + PBLK*2;
            int v2 = (s2 < k) ? keep_ids[s2] : 0;   // prefetch next row id
            H[s*128 + j] = val;
            lmax = fmaxf(lmax, val); lsum += val;
            s = s2; v = v2;
        }
        __shared__ float shm[256], shs[256];
        shm[t] = lmax; shs[t] = lsum;
        __syncthreads();
        if (sub == 0) {
            lmax = fmaxf(shm[j], shm[j+128]);
            lsum = shs[j] + shs[j+128];
            atomicMaxF(&rbuf[layer*256 + j], lmax);
            atomicAdd(&rbuf[layer*256 + 128 + j], lsum);
        }
    } else {
        // two-phase edge compaction: 1 global atomic per block
        int eb = b - PBLK, lane = t & 63;
        int ec = *ecntP;
        __shared__ int s_base, s_cur;
        __shared__ int red[256];
        int cnt = 0;
        for (int base = eb*256; base < ec; base += EBLK*256) {
            int e = base + t;
            if (e < ec) {
                int ns = remap[esrcP[e]], nd = remap[edstP[e]];
                cnt += (ns >= 0 && nd >= 0);
            }
        }
        red[t] = cnt; __syncthreads();
        for (int st = 128; st > 0; st >>= 1) { if (t < st) red[t] += red[t+st]; __syncthreads(); }
        if (t == 0) { s_base = atomicAdd(ecntN, red[0]); s_cur = 0; }
        __syncthreads();
        for (int base = eb*256; base < ec; base += EBLK*256) {
            int e = base + t;
            bool keep = false; int ns = 0, nd = 0;
            if (e < ec) {
                ns = remap[esrcP[e]]; nd = remap[edstP[e]];
                keep = (ns >= 0 && nd >= 0);
            }
            unsigned long long m = __ballot(keep);
            int wcnt = __popcll(m);
            int wbase = 0;
            if (lane == 0 && wcnt) wbase = atomicAdd(&s_cur, wcnt);
            wbase = __shfl(wbase, 0);
            if (keep) {
                int pos = s_base + wbase + __popcll(m & ((1ULL << lane) - 1));
                esrcN[pos] = ns; edstN[pos] = nd;
            }
        }
    }
}

// ---------------------------------------------------------------- MLP head
__global__ void k_lin1(const float* __restrict__ rbuf, const float* __restrict__ w1,
                       float* __restrict__ z1pre) {
    int kc = blockIdx.x / 5, jc = blockIdx.x % 5;
    int j = jc*256 + threadIdx.x;
    float acc = 0.0f;
    for (int i = kc*256; i < kc*256 + 256; i++) {
        float rv = rbuf[i];
        if ((i & 255) >= 128) rv *= c_invk[i >> 8];
        acc += rv * w1[i*1280 + j];
    }
    atomicAdd(&z1pre[j], acc);
}

__global__ __launch_bounds__(256) void k_lin2(const float* __restrict__ z1pre, const float* __restrict__ b1,
                                              const float* __restrict__ w2, const float* __restrict__ b2,
                                              const float* __restrict__ prelua, float* __restrict__ out) {
    int t = threadIdx.x;
    float a = prelua[0];
    float acc[8];
    #pragma unroll
    for (int o = 0; o < 8; o++) acc[o] = 0.0f;
    for (int kk = t; kk < 1280; kk += 256) {
        float z = z1pre[kk] + b1[kk];
        z = (z > 0.0f) ? z : a*z;
        #pragma unroll
        for (int o = 0; o < 8; o++) acc[o] += z * w2[kk*8 + o];
    }
    __shared__ float red[256];
    __shared__ float zo[8];
    for (int o = 0; o < 8; o++) {
        red[t] = acc[o]; __syncthreads();
        for (int s = 128; s > 0; s >>= 1) { if (t < s) red[t] += red[t+s]; __syncthreads(); }
        if (t == 0) { float z = red[0] + b2[o]; zo[o] = (z > 0.0f) ? z : a*z; }
        __syncthreads();
    }
    if (t == 0) {
        float mn = zo[0];
        for (int o = 1; o < 8; o++) mn = fminf(mn, zo[o]);
        float v[8], mx = -3.402823e38f;
        for (int o = 0; o < 8; o++) { v[o] = zo[o] - mn; mx = fmaxf(mx, v[o]); }
        float sm = 0.0f;
        for (int o = 0; o < 8; o++) { v[o] = v[o] / mx; sm += v[o]; }
        for (int o = 0; o < 8; o++) out[o] = v[o] / sm;
    }
}

// ---------------------------------------------------------------- launch
extern "C" void kernel_launch(void* const* d_in, const int* in_sizes, int n_in,
                              void* d_out, int out_size, void* d_ws, size_t ws_size,
                              hipStream_t stream) {
    const float* x      = (const float*)d_in[0];
    const int*   eidx   = (const int*)  d_in[1];
    const float* W1     = (const float*)d_in[2];
    const float* V1     = (const float*)d_in[3];
    const float* Ws     = (const float*)d_in[4];
    const float* Vs     = (const float*)d_in[5];
    const float* convb  = (const float*)d_in[6];
    const float* bng    = (const float*)d_in[7];
    const float* bnb    = (const float*)d_in[8];
    const float* bnm    = (const float*)d_in[9];
    const float* bnv    = (const float*)d_in[10];
    const float* poolp  = (const float*)d_in[11];
    const float* prelua = (const float*)d_in[12];
    const float* w1     = (const float*)d_in[13];
    const float* b1     = (const float*)d_in[14];
    const float* w2     = (const float*)d_in[15];
    const float* b2     = (const float*)d_in[16];
    float* out = (float*)d_out;

    float* wsf  = (float*)d_ws;
    float* H    = wsf;
    float* HW   = H    + (size_t)NMAX*128;
    float* AGG  = HW   + (size_t)NMAX*128;
    float* dinv = AGG  + (size_t)NMAX*128;
    float* score= dinv + NMAX;
    float* rbuf = score+ NMAX;
    float* pnorm= rbuf + 2560;
    float* z1pre= pnorm+ 16;
    unsigned* keys = (unsigned*)(z1pre + 1280);
    int* esrcA  = (int*)(keys + NMAX);
    int* edstA  = esrcA + NEDGE;
    int* esrcB  = edstA + NEDGE;
    int* edstB  = esrcB + NEDGE;
    int* csr    = edstB + NEDGE;
    int* deg    = csr  + NEDGE;      // deg[NMAX] + ghist[2048]: one memset
    int* ghist  = deg  + NMAX;
    int* offs   = ghist + 2048;
    int* cursor = offs + NMAX;
    int* remap  = cursor + NMAX;
    int* keep_ids = remap + NMAX;
    unsigned* ckey = (unsigned*)(keep_ids + NMAX);
    int* cidx   = (int*)(ckey + NMAX);
    int* bpart  = cidx + NMAX;       // 64
    int* ecnt   = bpart + 64;        // 16
    int* selbuf = ecnt + 16;         // 16

    static const int NS[10] = {40000,32000,25600,20480,16384,13108,10487,8390,6712,5370};
    static const int KS[10] = {32000,25600,20480,16384,13108,10487,8390,6712,5370,4296};

    k_init<<<2500, 256, 0, stream>>>(eidx, esrcA, edstA, poolp, rbuf, pnorm, ecnt);
    hipMemsetAsync(z1pre, 0, 1280*sizeof(float), stream);

    for (int i = 0; i < 10; i++) {
        int n = NS[i], k = KS[i];
        int chunk = (n + SB - 1) / SB;
        int* esrcP = (i & 1) ? esrcB : esrcA;
        int* edstP = (i & 1) ? edstB : edstA;
        int* esrcN = (i & 1) ? esrcA : esrcB;
        int* edstN = (i & 1) ? edstA : edstB;

        hipMemsetAsync(deg, 0, (size_t)(NMAX + 2048)*sizeof(int), stream);
        k_deg <<<2500, 256, 0, stream>>>(esrcP, edstP, deg, &ecnt[i]);
        k_s1  <<<SB, 256, 0, stream>>>(deg, bpart, n, chunk);
        k_s3  <<<SB, 256, 0, stream>>>(deg, bpart, offs, cursor, dinv, n, chunk);
        k_fill<<<2500, 256, 0, stream>>>(esrcP, edstP, cursor, csr, &ecnt[i]);

        if (i == 0) {
            k_gather0<<<n, 128, 0, stream>>>(x, W1, V1, convb,
                                             bng, bnb, bnm, bnv, poolp, pnorm, prelua,
                                             offs, deg, dinv, csr, AGG, score, keys);
        } else {
            k_gemm<<<(n + GRB - 1)/GRB, 128, 0, stream>>>(H, Ws + (size_t)(i-1)*16384,
                                                          Vs + (size_t)(i-1)*16384,
                                                          convb + i*128, HW, AGG, n);
            k_gather<<<n, 128, 0, stream>>>(HW, AGG, offs, deg, dinv, csr,
                                            bng, bnb, bnm, bnv, poolp, pnorm, prelua,
                                            score, keys, i);
        }

        k_hist   <<<32, 256, 0, stream>>>(keys, ghist, n);
        k_sel1   <<<1, 1024, 0, stream>>>(ghist, selbuf, k);
        k_collect<<<64, 256, 0, stream>>>(keys, selbuf, ckey, cidx, n);
        k_refine <<<1, 1024, 0, stream>>>(ckey, cidx, selbuf, n);
        k_compact<<<64, 256, 0, stream>>>(keys, selbuf, remap, keep_ids, n);

        k_pool<<<PBLK + EBLK, 256, 0, stream>>>(AGG, score, keep_ids, remap, H, rbuf,
                                                esrcP, edstP, esrcN, edstN,
                                                &ecnt[i], &ecnt[i+1], k, i);
    }

    k_lin1<<<50, 256, 0, stream>>>(rbuf, w1, z1pre);
    k_lin2<<<1, 256, 0, stream>>>(z1pre, b1, w2, b2, prelua, out);
}